// Round 1
// baseline (385.667 us; speedup 1.0000x reference)
//
#include <hip/hip_runtime.h>

#define BR_N     1000000
#define DIM      128
#define TILE_M   64
#define NTILES   (BR_N / TILE_M)   /* 15625, exact */
#define NTHREADS 512
#define NBLOCKS  1024

typedef __attribute__((ext_vector_type(8))) short    bf16x8;
typedef __attribute__((ext_vector_type(4))) float    f32x4;
typedef __attribute__((ext_vector_type(4))) unsigned u32x4;

// f32 -> bf16 round-to-nearest-even
static __device__ __forceinline__ unsigned f2bf(float f) {
    union { float f; unsigned u; } v; v.f = f;
    return (v.u + 0x7fffu + ((v.u >> 16) & 1u)) >> 16;
}
static __device__ __forceinline__ unsigned pk2(float a, float b) {
    return f2bf(a) | (f2bf(b) << 16);
}

union FragU { bf16x8 v; u32x4 u; };

static __device__ __forceinline__ bf16x8 cvt8(const f32x4 a, const f32x4 b) {
    FragU r;
    r.u.x = pk2(a.x, a.y);
    r.u.y = pk2(a.z, a.w);
    r.u.z = pk2(b.x, b.y);
    r.u.w = pk2(b.z, b.w);
    return r.v;
}

// out = sigmoid(s@Vs.T + o@Vo.T) * relu(s@Ws.T + o@Wo.T + s*(o.w))
__global__ __launch_bounds__(NTHREADS, 2)
void relup_kernel(const float* __restrict__ S, const float* __restrict__ O,
                  const float* __restrict__ Vs, const float* __restrict__ Vo,
                  const float* __restrict__ Ws, const float* __restrict__ Wo,
                  const float* __restrict__ W1, float* __restrict__ out)
{
    // bf16 tiles, row stride 256 B, byte-swizzled: 16B granule g of row r lives at (g ^ (r&7))
    __shared__ __align__(16) unsigned char sT[TILE_M * 256];
    __shared__ __align__(16) unsigned char oT[TILE_M * 256];
    __shared__ float dotv[TILE_M];

    const int tid  = threadIdx.x;
    const int lane = tid & 63;
    const int wv   = tid >> 6;       // wave id 0..7, owns output cols [wv*16, wv*16+16)
    const int c0   = wv << 4;

    // ---- preload weight B-fragments into registers (held for whole kernel) ----
    // B = W.T, so B-frag(kk): lane holds W[c0+(lane&15)][kk*32 + (lane>>4)*8 + j], 8 contiguous floats
    bf16x8 fVs[4], fVo[4], fWs[4], fWo[4];
    {
        const int wr = c0 + (lane & 15);
        const int wc = (lane >> 4) << 3;
        #pragma unroll
        for (int kk = 0; kk < 4; ++kk) {
            const int off = wr * DIM + kk * 32 + wc;
            fVs[kk] = cvt8(*(const f32x4*)(Vs + off), *(const f32x4*)(Vs + off + 4));
            fVo[kk] = cvt8(*(const f32x4*)(Vo + off), *(const f32x4*)(Vo + off + 4));
            fWs[kk] = cvt8(*(const f32x4*)(Ws + off), *(const f32x4*)(Ws + off + 4));
            fWo[kk] = cvt8(*(const f32x4*)(Wo + off), *(const f32x4*)(Wo + off + 4));
        }
    }

    // staging assignment: thread -> (row 0..63, 16-float segment 0..7)
    const int str = tid >> 3;
    const int seg = tid & 7;
    const int swS = (str & 7) << 4;
    const int sb0 = str * 256 + ((seg * 32) ^ swS);
    const int sb1 = str * 256 + (((seg * 32) + 16) ^ swS);

    for (int t = blockIdx.x; t < NTILES; t += gridDim.x) {
        const int row0 = t * TILE_M;

        // ---- stage s,o -> LDS bf16 (swizzled); dot(o,w) in f32 ----
        {
            const float* sp = S + (row0 + str) * DIM + seg * 16;
            const float* op = O + (row0 + str) * DIM + seg * 16;
            const float* wp = W1 + seg * 16;
            f32x4 s0 = ((const f32x4*)sp)[0], s1 = ((const f32x4*)sp)[1];
            f32x4 s2 = ((const f32x4*)sp)[2], s3 = ((const f32x4*)sp)[3];
            f32x4 o0 = ((const f32x4*)op)[0], o1 = ((const f32x4*)op)[1];
            f32x4 o2 = ((const f32x4*)op)[2], o3 = ((const f32x4*)op)[3];
            f32x4 w0 = ((const f32x4*)wp)[0], w1 = ((const f32x4*)wp)[1];
            f32x4 w2 = ((const f32x4*)wp)[2], w3 = ((const f32x4*)wp)[3];

            float p = o0.x*w0.x + o0.y*w0.y + o0.z*w0.z + o0.w*w0.w
                    + o1.x*w1.x + o1.y*w1.y + o1.z*w1.z + o1.w*w1.w
                    + o2.x*w2.x + o2.y*w2.y + o2.z*w2.z + o2.w*w2.w
                    + o3.x*w3.x + o3.y*w3.y + o3.z*w3.z + o3.w*w3.w;

            u32x4 pa = { pk2(s0.x,s0.y), pk2(s0.z,s0.w), pk2(s1.x,s1.y), pk2(s1.z,s1.w) };
            u32x4 pb = { pk2(s2.x,s2.y), pk2(s2.z,s2.w), pk2(s3.x,s3.y), pk2(s3.z,s3.w) };
            u32x4 pc = { pk2(o0.x,o0.y), pk2(o0.z,o0.w), pk2(o1.x,o1.y), pk2(o1.z,o1.w) };
            u32x4 pd = { pk2(o2.x,o2.y), pk2(o2.z,o2.w), pk2(o3.x,o3.y), pk2(o3.z,o3.w) };
            *(u32x4*)(sT + sb0) = pa;
            *(u32x4*)(sT + sb1) = pb;
            *(u32x4*)(oT + sb0) = pc;
            *(u32x4*)(oT + sb1) = pd;

            p += __shfl_xor(p, 1);
            p += __shfl_xor(p, 2);
            p += __shfl_xor(p, 4);
            if (seg == 0) dotv[str] = p;
        }
        __syncthreads();

        // ---- compute: 4 sub-blocks of 16 rows ----
        #pragma unroll
        for (int b = 0; b < 4; ++b) {
            const int r0  = b << 4;
            const int ar  = r0 + (lane & 15);
            const int swA = (ar & 7) << 4;
            const int acb = (lane >> 4) << 4;     // byte offset of this lane's 8 bf16 within a 64B k-step
            bf16x8 fs[4], fo[4];
            #pragma unroll
            for (int kk = 0; kk < 4; ++kk) {
                const int cb = ((kk << 6) + acb) ^ swA;
                fs[kk] = *(const bf16x8*)(sT + ar * 256 + cb);
                fo[kk] = *(const bf16x8*)(oT + ar * 256 + cb);
            }
            f32x4 accg = {0.f, 0.f, 0.f, 0.f};
            f32x4 accd = {0.f, 0.f, 0.f, 0.f};
            #pragma unroll
            for (int kk = 0; kk < 4; ++kk) {
                accg = __builtin_amdgcn_mfma_f32_16x16x32_bf16(fs[kk], fVs[kk], accg, 0, 0, 0);
                accg = __builtin_amdgcn_mfma_f32_16x16x32_bf16(fo[kk], fVo[kk], accg, 0, 0, 0);
                accd = __builtin_amdgcn_mfma_f32_16x16x32_bf16(fs[kk], fWs[kk], accd, 0, 0, 0);
                accd = __builtin_amdgcn_mfma_f32_16x16x32_bf16(fo[kk], fWo[kk], accd, 0, 0, 0);
            }
            // epilogue: C/D layout (measured): lane reg r -> row (lane>>4)*4+r, col lane&15
            const int col = c0 + (lane & 15);
            #pragma unroll
            for (int r = 0; r < 4; ++r) {
                const int row = r0 + ((lane >> 4) << 2) + r;
                const int gi  = (row0 + row) * DIM + col;
                const float sval  = S[gi];               // L2-hot: just staged
                const float inter = sval * dotv[row];
                const float gate  = 1.0f / (1.0f + __expf(-accg[r]));
                float dir = accd[r] + inter;
                dir = dir > 0.0f ? dir : 0.0f;
                out[gi] = gate * dir;
            }
        }
        __syncthreads();
    }
}

extern "C" void kernel_launch(void* const* d_in, const int* in_sizes, int n_in,
                              void* d_out, int out_size, void* d_ws, size_t ws_size,
                              hipStream_t stream) {
    const float* S  = (const float*)d_in[0];
    const float* O  = (const float*)d_in[1];
    const float* Vs = (const float*)d_in[2];
    const float* Vo = (const float*)d_in[3];
    const float* Ws = (const float*)d_in[4];
    const float* Wo = (const float*)d_in[5];
    const float* w  = (const float*)d_in[6];
    float* out = (float*)d_out;
    relup_kernel<<<NBLOCKS, NTHREADS, 0, stream>>>(S, O, Vs, Vo, Ws, Wo, w, out);
}